// Round 2
// baseline (797.401 us; speedup 1.0000x reference)
//
#include <hip/hip_runtime.h>
#include <hip/hip_bf16.h>

// Problem constants (reference: N=1048576, D=128, NUM_CLASS=100)
#define DFEAT 128
#define NCLASS 100
#define NTPAD 7      // 7 class-tiles of 16 = 112 padded classes (100..111 zero anchors)

typedef short bf16x8 __attribute__((ext_vector_type(8)));   // 8 bf16 = 4 VGPRs (MFMA A/B frag)
typedef float f32x4  __attribute__((ext_vector_type(4)));   // MFMA C/D frag

// fp32 -> bf16 round-to-nearest-even — used for anchors (one-time)
__device__ __forceinline__ short f2bf(float f) {
    unsigned u = __float_as_uint(f);
    u += 0x7fffu + ((u >> 16) & 1u);
    return (short)(u >> 16);
}

// anchors pre-scaled by log2(e): scores come out of the MFMA already in base-2
// domain, so softmax uses native v_exp_f32/v_log_f32 (which ARE exp2/log2) with
// no per-element multiply; finalize multiplies the scalar by ln2 once.
__device__ __forceinline__ bf16x8 cvt8_rne_scaled(float4 f0, float4 f1, float sc) {
    bf16x8 v;
    v[0] = f2bf(f0.x * sc); v[1] = f2bf(f0.y * sc); v[2] = f2bf(f0.z * sc); v[3] = f2bf(f0.w * sc);
    v[4] = f2bf(f1.x * sc); v[5] = f2bf(f1.y * sc); v[6] = f2bf(f1.z * sc); v[7] = f2bf(f1.w * sc);
    return v;
}

// fp32x8 -> bf16x8 via v_perm_b32 (RTZ truncation): 4 instructions total (x side).
__device__ __forceinline__ bf16x8 cvt8_trunc(float4 f0, float4 f1) {
    union { bf16x8 v; unsigned u[4]; } r;
    r.u[0] = __builtin_amdgcn_perm(__float_as_uint(f0.y), __float_as_uint(f0.x), 0x07060302u);
    r.u[1] = __builtin_amdgcn_perm(__float_as_uint(f0.w), __float_as_uint(f0.z), 0x07060302u);
    r.u[2] = __builtin_amdgcn_perm(__float_as_uint(f1.y), __float_as_uint(f1.x), 0x07060302u);
    r.u[3] = __builtin_amdgcn_perm(__float_as_uint(f1.w), __float_as_uint(f1.z), 0x07060302u);
    return r.v;
}

// SWAPPED-OPERAND layout: mfma(anchors, x) gives C[class][sample]:
//   col = lane&15 = c  -> SAMPLE index within tile (this lane's own sample),
//   row = q*4+r        -> class-in-tile; with 7 t-tiles each lane holds 28
//                         class scores of sample c, classes {t*16 + q*4 + r}.
// Sum-exp is lane-local (28 exp2 + adds) + a 2-stage shfl_xor(16,32) reduce
// over q, and s_y needs NO shuffle at all: Y = 16t + 4q + r decomposes
// uniquely (r=Y&3, q=(Y>>2)&3, t=Y>>4), so exactly one lane owns class==Y;
// every lane subtracts its syn (0 elsewhere) and the end-of-kernel wave
// reduce collects it. This replaces the old 36-shuffle / 16-dependent-stage
// per-tile reduction (the latency chain holding ce_main at ~330us) with
// 2 shuffles / 2 stages.
__global__ __launch_bounds__(256, 2)
void ce_main(const float* __restrict__ x, const float* __restrict__ anchors,
             const int* __restrict__ y, int ntiles,
             float* __restrict__ total_ce, unsigned* __restrict__ gpres) {
    const int lane = threadIdx.x & 63;
    const int c    = lane & 15;   // sample-within-tile (MFMA col) / anchor A-row
    const int q    = lane >> 4;   // quad
    const int wid    = blockIdx.x * 4 + (threadIdx.x >> 6);
    const int nwaves = gridDim.x * 4;

    // ---- Preload anchor A-fragments (RNE, x log2e): A[row=lane&15][k=q*8+j]
    // (identical lane->element mapping as a B-frag build, so same addressing)
    const float LOG2E = 1.4426950408889634f;
    bf16x8 bf[NTPAD][4];
    #pragma unroll
    for (int t = 0; t < NTPAD; ++t) {
        const int col = t * 16 + c;
        #pragma unroll
        for (int kk = 0; kk < 4; ++kk) {
            if (col < NCLASS) {
                const float4* av = (const float4*)anchors + (size_t)col * (DFEAT / 4) + q * 2 + kk * 8;
                bf[t][kk] = cvt8_rne_scaled(av[0], av[1], LOG2E);
            } else {
                bf16x8 z = {0,0,0,0,0,0,0,0};
                bf[t][kk] = z;
            }
        }
    }

    float acc_ce = 0.f;                    // base-2 CE accumulator (x ln2 in finalize)
    unsigned pm0 = 0, pm1 = 0, pm2 = 0, pm3 = 0;   // presence bitmap in VGPRs (no LDS in loop)

    // ---- software pipeline: prefetch first tile's x-rows + label into registers
    float4 cur[8];
    int    curY = 0;
    int tile = wid;
    if (tile < ntiles) {
        const float4* xv = (const float4*)x + (size_t)(tile * 16 + c) * (DFEAT / 4) + q * 2;
        #pragma unroll
        for (int kk = 0; kk < 4; ++kk) { cur[2 * kk] = xv[kk * 8]; cur[2 * kk + 1] = xv[kk * 8 + 1]; }
        curY = y[tile * 16 + c];
    }

    for (; tile < ntiles; tile += nwaves) {
        // consume the prefetched data first (s_waitcnt vmcnt lands here)
        bf16x8 af[4];
        #pragma unroll
        for (int kk = 0; kk < 4; ++kk) af[kk] = cvt8_trunc(cur[2 * kk], cur[2 * kk + 1]);
        const int Yl = curY;               // label of THIS lane's sample c

        // issue next tile's loads NOW; they complete under this tile's compute
        const int nxt = tile + nwaves;     // wave-uniform branch
        if (nxt < ntiles) {
            const float4* xv = (const float4*)x + (size_t)(nxt * 16 + c) * (DFEAT / 4) + q * 2;
            #pragma unroll
            for (int kk = 0; kk < 4; ++kk) { cur[2 * kk] = xv[kk * 8]; cur[2 * kk + 1] = xv[kk * 8 + 1]; }
            curY = y[nxt * 16 + c];
        }

        // presence: 4x(cmp+cndmask+or) in VGPRs, replaces per-tile LDS atomicOr
        {
            const int w = Yl >> 5;
            const unsigned b = 1u << (Yl & 31);
            pm0 |= (w == 0) ? b : 0u;
            pm1 |= (w == 1) ? b : 0u;
            pm2 |= (w == 2) ? b : 0u;
            pm3 |= (w == 3) ? b : 0u;
        }

        // ---- 28 MFMAs, operands SWAPPED: scores[112 classes][16 samples]
        f32x4 acc[NTPAD];
        #pragma unroll
        for (int t = 0; t < NTPAD; ++t) { f32x4 z = {0.f, 0.f, 0.f, 0.f}; acc[t] = z; }
        #pragma unroll
        for (int kk = 0; kk < 4; ++kk)
            #pragma unroll
            for (int t = 0; t < NTPAD; ++t)
                acc[t] = __builtin_amdgcn_mfma_f32_16x16x32_bf16(bf[t][kk], af[kk], acc[t], 0, 0, 0);

        // ---- lane-local softmax pieces over this lane's 28 classes.
        // No max pass: scaled scores |s| < ~101 << 127 (exp2 range), padded
        // cols contribute 2^0 = 1 each, subtracted as the constant 12.
        const int yq = Yl - (q << 2);      // class==Yl  <=>  16t + r == yq
        float lp[4] = {0.f, 0.f, 0.f, 0.f};
        float syn = 0.f;
        #pragma unroll
        for (int t = 0; t < NTPAD; ++t) {
            #pragma unroll
            for (int r = 0; r < 4; ++r) {
                const float s = acc[t][r];
                lp[r] += exp2f(s);                    // native v_exp_f32, 4 parallel chains
                if (yq == t * 16 + r) syn = s;        // unique owner lane
            }
        }
        float l = (lp[0] + lp[1]) + (lp[2] + lp[3]);
        l += __shfl_xor(l, 16, 64);        // reduce over q: only 2 dependent
        l += __shfl_xor(l, 32, 64);        // cross-lane stages per tile
        acc_ce -= syn;                     // -s_y (scaled); only owner lane nonzero
        if (q == 0) acc_ce += __log2f(l - 12.0f);  // native v_log_f32: log2(sum - pads)
    }

    // ---- wave reduction + one atomic/wave
    acc_ce += __shfl_xor(acc_ce, 1, 64);
    acc_ce += __shfl_xor(acc_ce, 2, 64);
    acc_ce += __shfl_xor(acc_ce, 4, 64);
    acc_ce += __shfl_xor(acc_ce, 8, 64);
    acc_ce += __shfl_xor(acc_ce, 16, 64);
    acc_ce += __shfl_xor(acc_ce, 32, 64);
    if (lane == 0) atomicAdd(total_ce, acc_ce);

    // presence: wave OR-reduce (once per kernel), then 4 global atomics/wave
    #pragma unroll
    for (int s = 1; s <= 32; s <<= 1) {
        pm0 |= (unsigned)__shfl_xor((int)pm0, s, 64);
        pm1 |= (unsigned)__shfl_xor((int)pm1, s, 64);
        pm2 |= (unsigned)__shfl_xor((int)pm2, s, 64);
        pm3 |= (unsigned)__shfl_xor((int)pm3, s, 64);
    }
    if (lane == 0) {
        atomicOr(&gpres[0], pm0);
        atomicOr(&gpres[1], pm1);
        atomicOr(&gpres[2], pm2);
        atomicOr(&gpres[3], pm3);
    }
}

__global__ void ce_finalize(const float* __restrict__ total_ce,
                            const unsigned* __restrict__ pres,
                            float* __restrict__ out, int nsamples) {
    if (threadIdx.x == 0 && blockIdx.x == 0) {
        int np = 0;
        #pragma unroll
        for (int i = 0; i < 4; ++i) np += __popc(pres[i]);
        // total_ce is in log2 units -> x ln2; then x (n_present / N)
        out[0] = total_ce[0] * 0.69314718055994530942f * ((float)np / (float)nsamples);
    }
}

extern "C" void kernel_launch(void* const* d_in, const int* in_sizes, int n_in,
                              void* d_out, int out_size, void* d_ws, size_t ws_size,
                              hipStream_t stream) {
    const float* x       = (const float*)d_in[0];
    const float* anchors = (const float*)d_in[1];
    const int*   y       = (const int*)d_in[2];
    float* out = (float*)d_out;

    const int nsamples = in_sizes[0] / DFEAT;   // 1048576
    const int ntiles   = nsamples / 16;         // 65536

    float*    total = (float*)d_ws;                       // ws[0]: CE accumulator
    unsigned* pres  = (unsigned*)((char*)d_ws + 16);      // ws[16..31]: presence bitmap

    hipMemsetAsync(d_ws, 0, 64, stream);                  // ws is poisoned 0xAA each call
    ce_main<<<512, 256, 0, stream>>>(x, anchors, y, ntiles, total, pres);
    ce_finalize<<<1, 64, 0, stream>>>(total, pres, out, nsamples);
}

// Round 3
// 704.992 us; speedup vs baseline: 1.1311x; 1.1311x over previous
//
#include <hip/hip_runtime.h>
#include <hip/hip_bf16.h>

// Problem constants (reference: N=1048576, D=128, NUM_CLASS=100)
#define DFEAT 128
#define NCLASS 100
#define NTPAD 7      // 7 class-tiles of 16 = 112 padded classes (100..111 zero anchors)
#define NBLOCKS 512

typedef short bf16x8 __attribute__((ext_vector_type(8)));   // 8 bf16 = 4 VGPRs (MFMA A/B frag)
typedef float f32x4  __attribute__((ext_vector_type(4)));   // MFMA C/D frag

// fp32 -> bf16 round-to-nearest-even — used for anchors (one-time)
__device__ __forceinline__ short f2bf(float f) {
    unsigned u = __float_as_uint(f);
    u += 0x7fffu + ((u >> 16) & 1u);
    return (short)(u >> 16);
}

// anchors pre-scaled by log2(e): scores come out of the MFMA already in base-2
// domain, so softmax uses native v_exp_f32/v_log_f32 (which ARE exp2/log2) with
// no per-element multiply; finalize multiplies the scalar by ln2 once.
__device__ __forceinline__ bf16x8 cvt8_rne_scaled(float4 f0, float4 f1, float sc) {
    bf16x8 v;
    v[0] = f2bf(f0.x * sc); v[1] = f2bf(f0.y * sc); v[2] = f2bf(f0.z * sc); v[3] = f2bf(f0.w * sc);
    v[4] = f2bf(f1.x * sc); v[5] = f2bf(f1.y * sc); v[6] = f2bf(f1.z * sc); v[7] = f2bf(f1.w * sc);
    return v;
}

// fp32x8 -> bf16x8 via v_perm_b32 (RTZ truncation): 4 instructions total (x side).
__device__ __forceinline__ bf16x8 cvt8_trunc(float4 f0, float4 f1) {
    union { bf16x8 v; unsigned u[4]; } r;
    r.u[0] = __builtin_amdgcn_perm(__float_as_uint(f0.y), __float_as_uint(f0.x), 0x07060302u);
    r.u[1] = __builtin_amdgcn_perm(__float_as_uint(f0.w), __float_as_uint(f0.z), 0x07060302u);
    r.u[2] = __builtin_amdgcn_perm(__float_as_uint(f1.y), __float_as_uint(f1.x), 0x07060302u);
    r.u[3] = __builtin_amdgcn_perm(__float_as_uint(f1.w), __float_as_uint(f1.z), 0x07060302u);
    return r.v;
}

// SWAPPED-OPERAND layout: mfma(anchors, x) gives C[class][sample]:
//   col = lane&15 = c  -> SAMPLE index within tile (this lane's own sample),
//   row = q*4+r        -> class-in-tile; over 7 t-tiles each lane holds 28
//                         class scores of its own sample: classes {16t+4q+r}.
// Sum-exp is lane-local (28 exp2 + adds) + a 2-stage shfl_xor(16,32) reduce
// over q. s_y needs NO shuffle: Y = 16t+4q+r decomposes uniquely
// (r=Y&3, q=(Y>>2)&3, t=Y>>4) so exactly one lane owns class==Y; every lane
// subtracts its syn (0 elsewhere) and the end-of-kernel reduce collects it.
// (Replaces the old 36-shuffle / 16-dependent-stage per-tile reduction.)
//
// No global atomics, no workspace init: each block OVERWRITES its own ws slot
// (poison-safe), finalize reduces 512 partials. Dispatches: 2 (was 3).
__global__ __launch_bounds__(256, 2)
void ce_main(const float* __restrict__ x, const float* __restrict__ anchors,
             const int* __restrict__ y, int ntiles,
             float* __restrict__ ws_ce, unsigned* __restrict__ ws_pres) {
    const int lane = threadIdx.x & 63;
    const int c    = lane & 15;   // sample-within-tile (MFMA col) / anchor A-row
    const int q    = lane >> 4;   // quad
    const int w    = threadIdx.x >> 6;      // wave id within block
    const int wid    = blockIdx.x * 4 + w;
    const int nwaves = gridDim.x * 4;

    // ---- Preload anchor A-fragments (RNE, x log2e): A[row=lane&15][k=q*8+j]
    const float LOG2E = 1.4426950408889634f;
    bf16x8 bf[NTPAD][4];
    #pragma unroll
    for (int t = 0; t < NTPAD; ++t) {
        const int col = t * 16 + c;
        #pragma unroll
        for (int kk = 0; kk < 4; ++kk) {
            if (col < NCLASS) {
                const float4* av = (const float4*)anchors + (size_t)col * (DFEAT / 4) + q * 2 + kk * 8;
                bf[t][kk] = cvt8_rne_scaled(av[0], av[1], LOG2E);
            } else {
                bf16x8 z = {0,0,0,0,0,0,0,0};
                bf[t][kk] = z;
            }
        }
    }

    float acc_ce = 0.f;                    // base-2 CE accumulator (x ln2 in finalize)
    unsigned pm0 = 0, pm1 = 0, pm2 = 0, pm3 = 0;   // presence bitmap in VGPRs

    // ---- software pipeline: prefetch first tile's x-rows + label into registers
    float4 cur[8];
    int    curY = 0;
    int tile = wid;
    if (tile < ntiles) {
        const float4* xv = (const float4*)x + (size_t)(tile * 16 + c) * (DFEAT / 4) + q * 2;
        #pragma unroll
        for (int kk = 0; kk < 4; ++kk) { cur[2 * kk] = xv[kk * 8]; cur[2 * kk + 1] = xv[kk * 8 + 1]; }
        curY = y[tile * 16 + c];
    }

    for (; tile < ntiles; tile += nwaves) {
        // consume the prefetched data first (s_waitcnt vmcnt lands here)
        bf16x8 af[4];
        #pragma unroll
        for (int kk = 0; kk < 4; ++kk) af[kk] = cvt8_trunc(cur[2 * kk], cur[2 * kk + 1]);
        const int Yl = curY;               // label of THIS lane's sample c

        // issue next tile's loads NOW; they complete under this tile's compute
        const int nxt = tile + nwaves;     // wave-uniform branch
        if (nxt < ntiles) {
            const float4* xv = (const float4*)x + (size_t)(nxt * 16 + c) * (DFEAT / 4) + q * 2;
            #pragma unroll
            for (int kk = 0; kk < 4; ++kk) { cur[2 * kk] = xv[kk * 8]; cur[2 * kk + 1] = xv[kk * 8 + 1]; }
            curY = y[nxt * 16 + c];
        }

        // presence: 4x(cmp+cndmask+or) in VGPRs
        {
            const int ww = Yl >> 5;
            const unsigned b = 1u << (Yl & 31);
            pm0 |= (ww == 0) ? b : 0u;
            pm1 |= (ww == 1) ? b : 0u;
            pm2 |= (ww == 2) ? b : 0u;
            pm3 |= (ww == 3) ? b : 0u;
        }

        // ---- 28 MFMAs, operands SWAPPED: scores[112 classes][16 samples]
        f32x4 acc[NTPAD];
        #pragma unroll
        for (int t = 0; t < NTPAD; ++t) { f32x4 z = {0.f, 0.f, 0.f, 0.f}; acc[t] = z; }
        #pragma unroll
        for (int kk = 0; kk < 4; ++kk)
            #pragma unroll
            for (int t = 0; t < NTPAD; ++t)
                acc[t] = __builtin_amdgcn_mfma_f32_16x16x32_bf16(bf[t][kk], af[kk], acc[t], 0, 0, 0);

        // ---- lane-local softmax pieces over this lane's 28 classes.
        // No max pass: scaled scores |s| < ~101 << 127 (exp2 range), padded
        // cols contribute 2^0 = 1 each, subtracted as the constant 12.
        const int yq = Yl - (q << 2);      // class==Yl  <=>  16t + r == yq
        float lp[4] = {0.f, 0.f, 0.f, 0.f};
        float syn = 0.f;
        #pragma unroll
        for (int t = 0; t < NTPAD; ++t) {
            #pragma unroll
            for (int r = 0; r < 4; ++r) {
                const float s = acc[t][r];
                lp[r] += exp2f(s);                    // native v_exp_f32, 4 parallel chains
                if (yq == t * 16 + r) syn = s;        // unique owner lane
            }
        }
        float l = (lp[0] + lp[1]) + (lp[2] + lp[3]);
        l += __shfl_xor(l, 16, 64);        // reduce over q: only 2 dependent
        l += __shfl_xor(l, 32, 64);        // cross-lane stages per tile
        acc_ce -= syn;                     // -s_y (scaled); only owner lane nonzero
        if (q == 0) acc_ce += __log2f(l - 12.0f);  // native v_log_f32: log2(sum - pads)
    }

    // ---- wave reduction
    acc_ce += __shfl_xor(acc_ce, 1, 64);
    acc_ce += __shfl_xor(acc_ce, 2, 64);
    acc_ce += __shfl_xor(acc_ce, 4, 64);
    acc_ce += __shfl_xor(acc_ce, 8, 64);
    acc_ce += __shfl_xor(acc_ce, 16, 64);
    acc_ce += __shfl_xor(acc_ce, 32, 64);
    #pragma unroll
    for (int s = 1; s <= 32; s <<= 1) {
        pm0 |= (unsigned)__shfl_xor((int)pm0, s, 64);
        pm1 |= (unsigned)__shfl_xor((int)pm1, s, 64);
        pm2 |= (unsigned)__shfl_xor((int)pm2, s, 64);
        pm3 |= (unsigned)__shfl_xor((int)pm3, s, 64);
    }

    // ---- block reduction via LDS (no atomics), one overwrite-write per block
    __shared__ float    sf[4];
    __shared__ unsigned sp[4][4];
    if (lane == 0) {
        sf[w] = acc_ce;
        sp[w][0] = pm0; sp[w][1] = pm1; sp[w][2] = pm2; sp[w][3] = pm3;
    }
    __syncthreads();
    if (threadIdx.x == 0)
        ws_ce[blockIdx.x] = (sf[0] + sf[1]) + (sf[2] + sf[3]);
    if (threadIdx.x < 4)
        ws_pres[blockIdx.x * 4 + threadIdx.x] =
            sp[0][threadIdx.x] | sp[1][threadIdx.x] | sp[2][threadIdx.x] | sp[3][threadIdx.x];
}

__global__ __launch_bounds__(256)
void ce_finalize(const float* __restrict__ ws_ce,
                 const unsigned* __restrict__ ws_pres,
                 float* __restrict__ out, int nsamples) {
    const int t    = threadIdx.x;
    const int lane = t & 63;
    const int w    = t >> 6;

    float s = ws_ce[t] + ws_ce[t + 256];
    unsigned p0 = ws_pres[t * 4 + 0] | ws_pres[(t + 256) * 4 + 0];
    unsigned p1 = ws_pres[t * 4 + 1] | ws_pres[(t + 256) * 4 + 1];
    unsigned p2 = ws_pres[t * 4 + 2] | ws_pres[(t + 256) * 4 + 2];
    unsigned p3 = ws_pres[t * 4 + 3] | ws_pres[(t + 256) * 4 + 3];

    #pragma unroll
    for (int d = 1; d <= 32; d <<= 1) {
        s  += __shfl_xor(s, d, 64);
        p0 |= (unsigned)__shfl_xor((int)p0, d, 64);
        p1 |= (unsigned)__shfl_xor((int)p1, d, 64);
        p2 |= (unsigned)__shfl_xor((int)p2, d, 64);
        p3 |= (unsigned)__shfl_xor((int)p3, d, 64);
    }

    __shared__ float    sf[4];
    __shared__ unsigned sp[4][4];
    if (lane == 0) {
        sf[w] = s;
        sp[w][0] = p0; sp[w][1] = p1; sp[w][2] = p2; sp[w][3] = p3;
    }
    __syncthreads();
    if (t == 0) {
        float tot = (sf[0] + sf[1]) + (sf[2] + sf[3]);
        int np = 0;
        #pragma unroll
        for (int i = 0; i < 4; ++i)
            np += __popc(sp[0][i] | sp[1][i] | sp[2][i] | sp[3][i]);
        // tot is in log2 units -> x ln2; then x (n_present / N)
        out[0] = tot * 0.69314718055994530942f * ((float)np / (float)nsamples);
    }
}

extern "C" void kernel_launch(void* const* d_in, const int* in_sizes, int n_in,
                              void* d_out, int out_size, void* d_ws, size_t ws_size,
                              hipStream_t stream) {
    const float* x       = (const float*)d_in[0];
    const float* anchors = (const float*)d_in[1];
    const int*   y       = (const int*)d_in[2];
    float* out = (float*)d_out;

    const int nsamples = in_sizes[0] / DFEAT;   // 1048576
    const int ntiles   = nsamples / 16;         // 65536

    // ws layout (poison-safe: every word read by finalize is overwritten first):
    //   [0, 2048)      float  ws_ce[512]    — per-block CE partials (log2 units)
    //   [2048, 10240)  uint   ws_pres[512*4]— per-block presence bitmaps
    float*    ws_ce   = (float*)d_ws;
    unsigned* ws_pres = (unsigned*)((char*)d_ws + 2048);

    ce_main<<<NBLOCKS, 256, 0, stream>>>(x, anchors, y, ntiles, ws_ce, ws_pres);
    ce_finalize<<<1, 256, 0, stream>>>(ws_ce, ws_pres, out, nsamples);
}